// Round 27
// baseline (121.021 us; speedup 1.0000x reference)
//
#include <hip/hip_runtime.h>
#include <hip/hip_bf16.h>
#include <stdint.h>
#include <float.h>

#define B_ 2
#define N_ 8192
#define C_ 64
#define K_ 16
#define D_IN 131     // 2C+3
#define QPB 16       // queries per block (4 waves x 4 queries)
#define QPW 4        // queries per wave
#define CAP 192      // survivor buffer capacity per query (E~64, sd~14 -> ~9 sigma)
#define SAMPLE_N 2048

typedef __attribute__((ext_vector_type(8))) short short8v;
typedef __attribute__((ext_vector_type(4))) float f32x4;
typedef unsigned long long ull;

// sentinel: larger than any real key, but FINITE as f64 (NaN would break fmin/fmax)
#define SENT_U64 0x7F7FFFFFFFFFFFFFull

__device__ __forceinline__ float sq3(float x, float y, float z) {
#pragma clang fp contract(off)
  return (x * x + y * y) + z * z;
}

__device__ __forceinline__ uint64_t shfl_xor_u64(uint64_t x, int mask) {
  int lo = __shfl_xor((int)(uint32_t)(x & 0xffffffffull), mask, 64);
  int hi = __shfl_xor((int)(uint32_t)(x >> 32), mask, 64);
  return ((uint64_t)(uint32_t)hi << 32) | (uint32_t)lo;
}

__device__ __forceinline__ double shfl_xor_f64(double x, int mask) {
  return __builtin_bit_cast(double, shfl_xor_u64(__builtin_bit_cast(uint64_t, x), mask));
}

__device__ __forceinline__ uint64_t pack_key_u64(float d, int idx) {
  return ((uint64_t)__float_as_uint(d) << 32) | (uint32_t)idx;
}

__device__ __forceinline__ short bfs(float x) {
  return __builtin_bit_cast(short, __float2bfloat16(x));
}

// branchless sorted-insert: precondition key < hd[15]; 15-stage min/max ladder.
__device__ __forceinline__ void insert16(double* hd, double key) {
  hd[15] = key;
#pragma unroll
  for (int z = 15; z >= 1; --z) {
    double a = hd[z - 1], b = hd[z];
    hd[z - 1] = fmin(a, b);
    hd[z] = fmax(a, b);
  }
}

// exact reference distance (bit-identical to all passing rounds)
__device__ __forceinline__ float exact_d(float qx, float qy, float qz, float xxq,
                                         float4 cd) {
  float dot2 = fmaf(qz, cd.z, fmaf(qy, cd.y, qx * cd.x));
  float dtmp;
  {
#pragma clang fp contract(off)
    dtmp = (xxq + cd.w) - dot2;
  }
  return fmaxf(dtmp, 0.0f);
}

// ---- merged prep: W -> bf16 fragments, coords -> c4 = (2cx,2cy,2cz,|c|^2) ----
__global__ __launch_bounds__(256) void prep(const float* __restrict__ coords,
                                            const float* __restrict__ W,
                                            __hip_bfloat16* __restrict__ wfrag,
                                            float4* __restrict__ c4) {
  int i = blockIdx.x * 256 + threadIdx.x;
  if (i < 4 * 5 * 64 * 8) {
    int j = i & 7;
    int l = (i >> 3) & 63;
    int ks = (i >> 9) % 5;
    int nt = (i >> 9) / 5;
    int k = ks * 32 + (l >> 4) * 8 + j;
    int col = nt * 16 + (l & 15);
    float v = (k < D_IN) ? W[k * 64 + col] : 0.0f;
    wfrag[i] = __float2bfloat16(v);
  }
  int j2 = i - 4 * 5 * 64 * 8;
  if (j2 >= 0 && j2 < B_ * N_) {
    float cx = coords[j2 * 3 + 0], cy = coords[j2 * 3 + 1], cz = coords[j2 * 3 + 2];
    c4[j2] = make_float4(2.0f * cx, 2.0f * cy, 2.0f * cz, sq3(cx, cy, cz));
  }
}

// ------- KNN: sampled threshold + single full collection, idx-only push,
//         software-pipelined (double-buffered cross-iteration prefetch) -------
__global__ __launch_bounds__(256) void knn_kernel(const float* __restrict__ coords,
                                                  const float4* __restrict__ c4,
                                                  int* __restrict__ idxout) {
  __shared__ int sbuf[QPB][CAP];
  __shared__ int scnt[QPB];
  const int t = threadIdx.x;
  const int w = t >> 6;                // wave 0..3
  const int lane = t & 63;
  const int blk = blockIdx.x;          // 1024 blocks: 512 per batch
  const int bb = blk >> 9;
  const int qbase = (blk & 511) * QPB;
  const float* cb = coords + (size_t)bb * N_ * 3;
  const float4* cg = c4 + (size_t)bb * N_;

  // this wave's 4 queries in registers (raw coords)
  float qx[QPW], qy[QPW], qz[QPW], xxq[QPW];
#pragma unroll
  for (int r = 0; r < QPW; ++r) {
    int n = qbase + w * QPW + r;
    qx[r] = cb[n * 3 + 0]; qy[r] = cb[n * 3 + 1]; qz[r] = cb[n * 3 + 2];
    xxq[r] = sq3(qx[r], qy[r], qz[r]);
  }
  if (t < QPB) scnt[t] = 0;
  __syncthreads();  // scnt visible before collection pushes

// proxy = q.(2c) - w : 3 fma (the -w rides the innermost fma operand-negation)
#define PROXY(r, cd) fmaf(qz[r], (cd).z, fmaf(qy[r], (cd).y, fmaf(qx[r], (cd).x, -(cd).w)))

#define LOAD8(p, base)            \
  p##0 = cg[(base) + lane];       \
  p##1 = cg[(base) + 64 + lane];  \
  p##2 = cg[(base) + 128 + lane]; \
  p##3 = cg[(base) + 192 + lane]; \
  p##4 = cg[(base) + 256 + lane]; \
  p##5 = cg[(base) + 320 + lane]; \
  p##6 = cg[(base) + 384 + lane]; \
  p##7 = cg[(base) + 448 + lane];

#define SAMPLE_BODY(p)                                                      \
  _Pragma("unroll")                                                         \
  for (int r = 0; r < QPW; ++r) {                                           \
    float p0 = PROXY(r, p##0);                                              \
    float p1 = PROXY(r, p##1);                                              \
    float p2 = PROXY(r, p##2);                                              \
    float p3 = PROXY(r, p##3);                                              \
    float p4 = PROXY(r, p##4);                                              \
    float p5 = PROXY(r, p##5);                                              \
    float p6 = PROXY(r, p##6);                                              \
    float p7 = PROXY(r, p##7);                                              \
    float a1 = fmaxf(p0, p1), b1 = fminf(p0, p1);                           \
    float a2 = fmaxf(p2, p3), b2 = fminf(p2, p3);                           \
    float a3 = fmaxf(p4, p5), b3 = fminf(p4, p5);                           \
    float a4 = fmaxf(p6, p7), b4 = fminf(p6, p7);                           \
    float h12 = fmaxf(a1, a2), s12 = fmaxf(fminf(a1, a2), fmaxf(b1, b2));   \
    float h34 = fmaxf(a3, a4), s34 = fmaxf(fminf(a3, a4), fmaxf(b3, b4));   \
    float hi = fmaxf(h12, h34);                                             \
    float se = fmaxf(fminf(h12, h34), fmaxf(s12, s34));                     \
    float nm2 = fmaxf(fminf(M1[r], hi), fmaxf(M2[r], se));                  \
    M1[r] = fmaxf(M1[r], hi);                                               \
    M2[r] = nm2;                                                            \
  }

#define COLLECT_BODY(p, base)                                                                     \
  _Pragma("unroll")                                                                               \
  for (int r = 0; r < QPW; ++r) {                                                                 \
    float p0 = PROXY(r, p##0);                                                                    \
    float p1 = PROXY(r, p##1);                                                                    \
    float p2 = PROXY(r, p##2);                                                                    \
    float p3 = PROXY(r, p##3);                                                                    \
    float p4 = PROXY(r, p##4);                                                                    \
    float p5 = PROXY(r, p##5);                                                                    \
    float p6 = PROXY(r, p##6);                                                                    \
    float p7 = PROXY(r, p##7);                                                                    \
    const int qr = w * QPW + r;                                                                   \
    if (p0 >= X[r]) { int pos = atomicAdd(&scnt[qr], 1); if (pos < CAP) sbuf[qr][pos] = (base) + lane; }        \
    if (p1 >= X[r]) { int pos = atomicAdd(&scnt[qr], 1); if (pos < CAP) sbuf[qr][pos] = (base) + 64 + lane; }   \
    if (p2 >= X[r]) { int pos = atomicAdd(&scnt[qr], 1); if (pos < CAP) sbuf[qr][pos] = (base) + 128 + lane; }  \
    if (p3 >= X[r]) { int pos = atomicAdd(&scnt[qr], 1); if (pos < CAP) sbuf[qr][pos] = (base) + 192 + lane; }  \
    if (p4 >= X[r]) { int pos = atomicAdd(&scnt[qr], 1); if (pos < CAP) sbuf[qr][pos] = (base) + 256 + lane; }  \
    if (p5 >= X[r]) { int pos = atomicAdd(&scnt[qr], 1); if (pos < CAP) sbuf[qr][pos] = (base) + 320 + lane; }  \
    if (p6 >= X[r]) { int pos = atomicAdd(&scnt[qr], 1); if (pos < CAP) sbuf[qr][pos] = (base) + 384 + lane; }  \
    if (p7 >= X[r]) { int pos = atomicAdd(&scnt[qr], 1); if (pos < CAP) sbuf[qr][pos] = (base) + 448 + lane; }  \
  }

  // ---- sample scan (first 2048): pipelined, per-lane top-2 LARGEST proxies ----
  float M1[QPW], M2[QPW];
#pragma unroll
  for (int r = 0; r < QPW; ++r) { M1[r] = -FLT_MAX; M2[r] = -FLT_MAX; }

  {
    float4 sa0, sa1, sa2, sa3, sa4, sa5, sa6, sa7;
    float4 sb0, sb1, sb2, sb3, sb4, sb5, sb6, sb7;
    LOAD8(sa, 0)
    for (int j0 = 0; j0 < SAMPLE_N; j0 += 1024) {
      LOAD8(sb, j0 + 512)
      SAMPLE_BODY(sa)
      {
        int jn = (j0 + 1024 < SAMPLE_N) ? (j0 + 1024) : 0;
        LOAD8(sa, jn)
      }
      SAMPLE_BODY(sb)
    }
  }

  // ---- threshold: 16th LARGEST of the 128 tracked values per query ----
  float A[QPW], Bt[QPW], pT[QPW];
#pragma unroll
  for (int r = 0; r < QPW; ++r) { A[r] = M1[r]; Bt[r] = M2[r]; pT[r] = -FLT_MAX; }
#pragma unroll
  for (int rd = 0; rd < 16; ++rd) {
#pragma unroll
    for (int r = 0; r < QPW; ++r) {
      float g = fmaxf(A[r], Bt[r]);
      g = fmaxf(g, __shfl_xor(g, 1, 64));
      g = fmaxf(g, __shfl_xor(g, 2, 64));
      g = fmaxf(g, __shfl_xor(g, 4, 64));
      g = fmaxf(g, __shfl_xor(g, 8, 64));
      g = fmaxf(g, __shfl_xor(g, 16, 64));
      g = fmaxf(g, __shfl_xor(g, 32, 64));
      pT[r] = g;
      A[r] = (A[r] == g) ? -FLT_MAX : A[r];
      Bt[r] = (Bt[r] == g) ? -FLT_MAX : Bt[r];
    }
  }
  float X[QPW];
#pragma unroll
  for (int r = 0; r < QPW; ++r) {
    float slop = 6e-6f * (fabsf(xxq[r]) + fabsf(pT[r])) + 1e-5f;
    X[r] = fminf(pT[r], xxq[r]) - 2.0f * slop;
  }

  // ---- collection (full N): pipelined, push INDEX only (proxy >= X) ----
  {
    float4 ca0, ca1, ca2, ca3, ca4, ca5, ca6, ca7;
    float4 cb0, cb1, cb2, cb3, cb4, cb5, cb6, cb7;
    LOAD8(ca, 0)
    for (int j0 = 0; j0 < N_; j0 += 1024) {
      LOAD8(cb, j0 + 512)
      COLLECT_BODY(ca, j0)
      {
        int jn = (j0 + 1024 < N_) ? (j0 + 1024) : 0;
        LOAD8(ca, jn)
      }
      COLLECT_BODY(cb, j0 + 512)
    }
  }
  __syncthreads();

  // ---- exact select: 16 lanes per query; recompute exact-d per survivor ----
  const int qloc = t >> 4;             // 0..15: query within block
  const int s16 = t & 15;              // lane within 16-lane select group
  const int n = qbase + qloc;

  const float fqx = cb[n * 3 + 0], fqy = cb[n * 3 + 1], fqz = cb[n * 3 + 2];
  const float fxx = sq3(fqx, fqy, fqz);

  double hd[16];
#pragma unroll
  for (int i = 0; i < 16; ++i) hd[i] = __builtin_bit_cast(double, SENT_U64);

  const int cntv = scnt[qloc];
  if (cntv > CAP) {
    // overflow fallback (statistically ~9 sigma): exact rescan, raw formula
    for (int j = s16; j < N_; j += 16) {
      float cx = cb[j * 3 + 0], cy = cb[j * 3 + 1], cz = cb[j * 3 + 2];
      float ww = sq3(cx, cy, cz);
      float dot = fmaf(fqz, cz, fmaf(fqy, cy, fqx * cx));
      float d2;
      {
#pragma clang fp contract(off)
        d2 = (fxx + ww) - 2.0f * dot;
      }
      d2 = fmaxf(d2, 0.0f);
      double k = __builtin_bit_cast(double, pack_key_u64(d2, j));
      if (k < hd[15]) insert16(hd, k);
    }
  } else {
    for (int i = s16; i < cntv; i += 16) {
      int idx = sbuf[qloc][i];
      float d = exact_d(fqx, fqy, fqz, fxx, cg[idx]);
      double k = __builtin_bit_cast(double, pack_key_u64(d, idx));
      if (k < hd[15]) insert16(hd, k);
    }
  }

  // merge the 16 per-lane sorted lists -> top-16 (ascending (dist,idx))
  int* myout = idxout + ((size_t)(bb * N_ + n)) * K_;
#pragma unroll
  for (int r = 0; r < 16; ++r) {
    double v = hd[0];
    v = fmin(v, shfl_xor_f64(v, 1));
    v = fmin(v, shfl_xor_f64(v, 2));
    v = fmin(v, shfl_xor_f64(v, 4));
    v = fmin(v, shfl_xor_f64(v, 8));
    if (__builtin_bit_cast(uint64_t, hd[0]) == __builtin_bit_cast(uint64_t, v)) {
#pragma unroll
      for (int z = 0; z < 15; ++z) hd[z] = hd[z + 1];
      hd[15] = __builtin_bit_cast(double, SENT_U64);
    }
    if (s16 == 0) myout[r] = (int)(uint32_t)__builtin_bit_cast(uint64_t, v);
  }
}

// ---- stage 2 (LDS-free): direct gather -> in-register A fragments -> MFMA ----
// A-matrix row = neighbor k (lane&15), cols: 0-63 fi | 64-127 nf-fi | 128-130 pos.
__global__ __launch_bounds__(256) void stage2(const float* __restrict__ coords,
                                              const float* __restrict__ feat,
                                              const int* __restrict__ idxbuf,
                                              const __hip_bfloat16* __restrict__ wfrag,
                                              const float* __restrict__ bias,
                                              float* __restrict__ out) {
  const int t = threadIdx.x;
  const int w = t >> 6;
  const int lane = t & 63;
  const int q = blockIdx.x * 4 + w;
  const int bb = q >> 13;
  const int n = q & (N_ - 1);
  const float* cb = coords + (size_t)bb * N_ * 3;
  const float* fb = feat + (size_t)bb * N_ * C_;
  const int* myidx = idxbuf + (size_t)q * K_;

  const int row = lane & 15;   // neighbor index k; also D's col = output channel
  const int g = lane >> 4;
  const int nb = myidx[row];

  const float* fq = fb + (size_t)n * C_;
  const float* fn = fb + (size_t)nb * C_;

  float4 fi0 = *(const float4*)&fq[g * 8];
  float4 fi1 = *(const float4*)&fq[g * 8 + 4];
  float4 fi2 = *(const float4*)&fq[32 + g * 8];
  float4 fi3 = *(const float4*)&fq[32 + g * 8 + 4];
  float4 nf0 = *(const float4*)&fn[g * 8];
  float4 nf1 = *(const float4*)&fn[g * 8 + 4];
  float4 nf2 = *(const float4*)&fn[32 + g * 8];
  float4 nf3 = *(const float4*)&fn[32 + g * 8 + 4];

  short8v a[5];
  a[0] = (short8v){bfs(fi0.x), bfs(fi0.y), bfs(fi0.z), bfs(fi0.w),
                   bfs(fi1.x), bfs(fi1.y), bfs(fi1.z), bfs(fi1.w)};
  a[1] = (short8v){bfs(fi2.x), bfs(fi2.y), bfs(fi2.z), bfs(fi2.w),
                   bfs(fi3.x), bfs(fi3.y), bfs(fi3.z), bfs(fi3.w)};
  a[2] = (short8v){bfs(nf0.x - fi0.x), bfs(nf0.y - fi0.y), bfs(nf0.z - fi0.z), bfs(nf0.w - fi0.w),
                   bfs(nf1.x - fi1.x), bfs(nf1.y - fi1.y), bfs(nf1.z - fi1.z), bfs(nf1.w - fi1.w)};
  a[3] = (short8v){bfs(nf2.x - fi2.x), bfs(nf2.y - fi2.y), bfs(nf2.z - fi2.z), bfs(nf2.w - fi2.w),
                   bfs(nf3.x - fi3.x), bfs(nf3.y - fi3.y), bfs(nf3.z - fi3.z), bfs(nf3.w - fi3.w)};
  if (g == 0) {
    a[4] = (short8v){bfs(cb[nb * 3 + 0] - cb[n * 3 + 0]),
                     bfs(cb[nb * 3 + 1] - cb[n * 3 + 1]),
                     bfs(cb[nb * 3 + 2] - cb[n * 3 + 2]),
                     0, 0, 0, 0, 0};
  } else {
    a[4] = (short8v){0, 0, 0, 0, 0, 0, 0, 0};
  }

  const short8v* wf = (const short8v*)wfrag;
#pragma unroll
  for (int nt = 0; nt < 4; ++nt) {
    f32x4 acc = {0.f, 0.f, 0.f, 0.f};
#pragma unroll
    for (int ks = 0; ks < 5; ++ks) {
      short8v bf = wf[(nt * 5 + ks) * 64 + lane];
      acc = __builtin_amdgcn_mfma_f32_16x16x32_bf16(a[ks], bf, acc, 0, 0, 0);
    }
    float bcol = bias[nt * 16 + row];
    float m = fmaxf(fmaxf(fmaxf(acc[0] + bcol, 0.f), fmaxf(acc[1] + bcol, 0.f)),
                    fmaxf(fmaxf(acc[2] + bcol, 0.f), fmaxf(acc[3] + bcol, 0.f)));
    m = fmaxf(m, __shfl_xor(m, 16, 64));
    m = fmaxf(m, __shfl_xor(m, 32, 64));
    if (lane < 16) out[(size_t)q * C_ + nt * 16 + row] = m;
  }
}

extern "C" void kernel_launch(void* const* d_in, const int* in_sizes, int n_in,
                              void* d_out, int out_size, void* d_ws, size_t ws_size,
                              hipStream_t stream) {
  const float* coords = (const float*)d_in[0];
  const float* feat = (const float*)d_in[1];
  const float* W = (const float*)d_in[2];
  const float* bias = (const float*)d_in[3];
  float* out = (float*)d_out;

  int* ws_idx = (int*)d_ws;                                   // B*N*K ints = 1 MiB
  char* p = (char*)d_ws + (size_t)B_ * N_ * K_ * sizeof(int);
  __hip_bfloat16* wfrag = (__hip_bfloat16*)p;                 // 20 KiB
  float4* c4 = (float4*)(p + 32768);                          // 256 KiB, 16B-aligned

  const int prep_elems = 4 * 5 * 64 * 8 + B_ * N_;
  prep<<<(prep_elems + 255) / 256, 256, 0, stream>>>(coords, W, wfrag, c4);
  knn_kernel<<<(B_ * N_) / QPB, 256, 0, stream>>>(coords, c4, ws_idx);
  stage2<<<(B_ * N_) / 4, 256, 0, stream>>>(coords, feat, ws_idx, wfrag, bias, out);
}

// Round 28
// 90.967 us; speedup vs baseline: 1.3304x; 1.3304x over previous
//
#include <hip/hip_runtime.h>
#include <hip/hip_bf16.h>
#include <stdint.h>
#include <float.h>

#define B_ 2
#define N_ 8192
#define C_ 64
#define K_ 16
#define D_IN 131     // 2C+3
#define QPB 16       // queries per block (4 waves x 4 queries)
#define QPW 4        // queries per wave
#define CAP 192      // survivor buffer capacity per query (E~64, sd~14 -> ~9 sigma)
#define SAMPLE_N 2048

typedef __attribute__((ext_vector_type(8))) short short8v;
typedef __attribute__((ext_vector_type(4))) float f32x4;
typedef unsigned long long ull;

// sentinel: larger than any real key, but FINITE as f64 (NaN would break fmin/fmax)
#define SENT_U64 0x7F7FFFFFFFFFFFFFull

__device__ __forceinline__ float sq3(float x, float y, float z) {
#pragma clang fp contract(off)
  return (x * x + y * y) + z * z;
}

__device__ __forceinline__ uint64_t shfl_xor_u64(uint64_t x, int mask) {
  int lo = __shfl_xor((int)(uint32_t)(x & 0xffffffffull), mask, 64);
  int hi = __shfl_xor((int)(uint32_t)(x >> 32), mask, 64);
  return ((uint64_t)(uint32_t)hi << 32) | (uint32_t)lo;
}

__device__ __forceinline__ double shfl_xor_f64(double x, int mask) {
  return __builtin_bit_cast(double, shfl_xor_u64(__builtin_bit_cast(uint64_t, x), mask));
}

__device__ __forceinline__ uint64_t pack_key_u64(float d, int idx) {
  return ((uint64_t)__float_as_uint(d) << 32) | (uint32_t)idx;
}

__device__ __forceinline__ short bfs(float x) {
  return __builtin_bit_cast(short, __float2bfloat16(x));
}

// branchless sorted-insert: precondition key < hd[15]; 15-stage min/max ladder.
__device__ __forceinline__ void insert16(double* hd, double key) {
  hd[15] = key;
#pragma unroll
  for (int z = 15; z >= 1; --z) {
    double a = hd[z - 1], b = hd[z];
    hd[z - 1] = fmin(a, b);
    hd[z] = fmax(a, b);
  }
}

// exact reference distance (bit-identical to all passing rounds)
__device__ __forceinline__ float exact_d(float qx, float qy, float qz, float xxq,
                                         float4 cd) {
  float dot2 = fmaf(qz, cd.z, fmaf(qy, cd.y, qx * cd.x));
  float dtmp;
  {
#pragma clang fp contract(off)
    dtmp = (xxq + cd.w) - dot2;
  }
  return fmaxf(dtmp, 0.0f);
}

// ---- merged prep: W -> bf16 fragments, coords -> c4 = (2cx,2cy,2cz,|c|^2) ----
__global__ __launch_bounds__(256) void prep(const float* __restrict__ coords,
                                            const float* __restrict__ W,
                                            __hip_bfloat16* __restrict__ wfrag,
                                            float4* __restrict__ c4) {
  int i = blockIdx.x * 256 + threadIdx.x;
  if (i < 4 * 5 * 64 * 8) {
    int j = i & 7;
    int l = (i >> 3) & 63;
    int ks = (i >> 9) % 5;
    int nt = (i >> 9) / 5;
    int k = ks * 32 + (l >> 4) * 8 + j;
    int col = nt * 16 + (l & 15);
    float v = (k < D_IN) ? W[k * 64 + col] : 0.0f;
    wfrag[i] = __float2bfloat16(v);
  }
  int j2 = i - 4 * 5 * 64 * 8;
  if (j2 >= 0 && j2 < B_ * N_) {
    float cx = coords[j2 * 3 + 0], cy = coords[j2 * 3 + 1], cz = coords[j2 * 3 + 2];
    c4[j2] = make_float4(2.0f * cx, 2.0f * cy, 2.0f * cz, sq3(cx, cy, cz));
  }
}

// ------- KNN: sampled threshold + single full collection, idx-only push -------
__global__ __launch_bounds__(256) void knn_kernel(const float* __restrict__ coords,
                                                  const float4* __restrict__ c4,
                                                  int* __restrict__ idxout) {
  __shared__ int sbuf[QPB][CAP];
  __shared__ int scnt[QPB];
  const int t = threadIdx.x;
  const int w = t >> 6;                // wave 0..3
  const int lane = t & 63;
  const int blk = blockIdx.x;          // 1024 blocks: 512 per batch
  const int bb = blk >> 9;
  const int qbase = (blk & 511) * QPB;
  const float* cb = coords + (size_t)bb * N_ * 3;
  const float4* cg = c4 + (size_t)bb * N_;

  // this wave's 4 queries in registers (raw coords)
  float qx[QPW], qy[QPW], qz[QPW], xxq[QPW];
#pragma unroll
  for (int r = 0; r < QPW; ++r) {
    int n = qbase + w * QPW + r;
    qx[r] = cb[n * 3 + 0]; qy[r] = cb[n * 3 + 1]; qz[r] = cb[n * 3 + 2];
    xxq[r] = sq3(qx[r], qy[r], qz[r]);
  }
  if (t < QPB) scnt[t] = 0;
  __syncthreads();  // scnt visible before collection pushes

// proxy = q.(2c) - w : 3 fma (the -w rides the innermost fma operand-negation)
#define PROXY(r, cd) fmaf(qz[r], (cd).z, fmaf(qy[r], (cd).y, fmaf(qx[r], (cd).x, -(cd).w)))

  // ---- sample scan (first 2048 candidates): per-lane top-2 LARGEST proxies ----
  float M1[QPW], M2[QPW];
#pragma unroll
  for (int r = 0; r < QPW; ++r) { M1[r] = -FLT_MAX; M2[r] = -FLT_MAX; }

  for (int j0 = 0; j0 < SAMPLE_N; j0 += 512) {
    float4 c0 = cg[j0 + lane];
    float4 c1 = cg[j0 + 64 + lane];
    float4 c2 = cg[j0 + 128 + lane];
    float4 c3 = cg[j0 + 192 + lane];
    float4 c4v = cg[j0 + 256 + lane];
    float4 c5 = cg[j0 + 320 + lane];
    float4 c6 = cg[j0 + 384 + lane];
    float4 c7 = cg[j0 + 448 + lane];
#pragma unroll
    for (int r = 0; r < QPW; ++r) {
      float p0 = PROXY(r, c0);
      float p1 = PROXY(r, c1);
      float p2 = PROXY(r, c2);
      float p3 = PROXY(r, c3);
      float p4 = PROXY(r, c4v);
      float p5 = PROXY(r, c5);
      float p6 = PROXY(r, c6);
      float p7 = PROXY(r, c7);
      float a1 = fmaxf(p0, p1), b1 = fminf(p0, p1);
      float a2 = fmaxf(p2, p3), b2 = fminf(p2, p3);
      float a3 = fmaxf(p4, p5), b3 = fminf(p4, p5);
      float a4 = fmaxf(p6, p7), b4 = fminf(p6, p7);
      float h12 = fmaxf(a1, a2), s12 = fmaxf(fminf(a1, a2), fmaxf(b1, b2));
      float h34 = fmaxf(a3, a4), s34 = fmaxf(fminf(a3, a4), fmaxf(b3, b4));
      float hi = fmaxf(h12, h34);
      float se = fmaxf(fminf(h12, h34), fmaxf(s12, s34));
      float nm2 = fmaxf(fminf(M1[r], hi), fmaxf(M2[r], se));
      M1[r] = fmaxf(M1[r], hi);
      M2[r] = nm2;
    }
  }

  // ---- threshold: 16th LARGEST of the 128 tracked values per query ----
  float A[QPW], Bt[QPW], pT[QPW];
#pragma unroll
  for (int r = 0; r < QPW; ++r) { A[r] = M1[r]; Bt[r] = M2[r]; pT[r] = -FLT_MAX; }
#pragma unroll
  for (int rd = 0; rd < 16; ++rd) {
#pragma unroll
    for (int r = 0; r < QPW; ++r) {
      float g = fmaxf(A[r], Bt[r]);
      g = fmaxf(g, __shfl_xor(g, 1, 64));
      g = fmaxf(g, __shfl_xor(g, 2, 64));
      g = fmaxf(g, __shfl_xor(g, 4, 64));
      g = fmaxf(g, __shfl_xor(g, 8, 64));
      g = fmaxf(g, __shfl_xor(g, 16, 64));
      g = fmaxf(g, __shfl_xor(g, 32, 64));
      pT[r] = g;
      A[r] = (A[r] == g) ? -FLT_MAX : A[r];
      Bt[r] = (Bt[r] == g) ? -FLT_MAX : Bt[r];
    }
  }
  float X[QPW];
#pragma unroll
  for (int r = 0; r < QPW; ++r) {
    float slop = 6e-6f * (fabsf(xxq[r]) + fabsf(pT[r])) + 1e-5f;
    X[r] = fminf(pT[r], xxq[r]) - 2.0f * slop;
  }

  // ---- collection (full N, 8-deep ILP): push INDEX only (proxy >= X) ----
  for (int j0 = 0; j0 < N_; j0 += 512) {
    const int ia = j0 + lane;
    float4 c0 = cg[ia];
    float4 c1 = cg[ia + 64];
    float4 c2 = cg[ia + 128];
    float4 c3 = cg[ia + 192];
    float4 c4v = cg[ia + 256];
    float4 c5 = cg[ia + 320];
    float4 c6 = cg[ia + 384];
    float4 c7 = cg[ia + 448];
#pragma unroll
    for (int r = 0; r < QPW; ++r) {
      float p0 = PROXY(r, c0);
      float p1 = PROXY(r, c1);
      float p2 = PROXY(r, c2);
      float p3 = PROXY(r, c3);
      float p4 = PROXY(r, c4v);
      float p5 = PROXY(r, c5);
      float p6 = PROXY(r, c6);
      float p7 = PROXY(r, c7);
      const int qr = w * QPW + r;
      if (p0 >= X[r]) { int pos = atomicAdd(&scnt[qr], 1); if (pos < CAP) sbuf[qr][pos] = ia; }
      if (p1 >= X[r]) { int pos = atomicAdd(&scnt[qr], 1); if (pos < CAP) sbuf[qr][pos] = ia + 64; }
      if (p2 >= X[r]) { int pos = atomicAdd(&scnt[qr], 1); if (pos < CAP) sbuf[qr][pos] = ia + 128; }
      if (p3 >= X[r]) { int pos = atomicAdd(&scnt[qr], 1); if (pos < CAP) sbuf[qr][pos] = ia + 192; }
      if (p4 >= X[r]) { int pos = atomicAdd(&scnt[qr], 1); if (pos < CAP) sbuf[qr][pos] = ia + 256; }
      if (p5 >= X[r]) { int pos = atomicAdd(&scnt[qr], 1); if (pos < CAP) sbuf[qr][pos] = ia + 320; }
      if (p6 >= X[r]) { int pos = atomicAdd(&scnt[qr], 1); if (pos < CAP) sbuf[qr][pos] = ia + 384; }
      if (p7 >= X[r]) { int pos = atomicAdd(&scnt[qr], 1); if (pos < CAP) sbuf[qr][pos] = ia + 448; }
    }
  }
  __syncthreads();

  // ---- exact select: 16 lanes per query; recompute exact-d per survivor ----
  const int qloc = t >> 4;             // 0..15: query within block
  const int s16 = t & 15;              // lane within 16-lane select group
  const int n = qbase + qloc;

  const float fqx = cb[n * 3 + 0], fqy = cb[n * 3 + 1], fqz = cb[n * 3 + 2];
  const float fxx = sq3(fqx, fqy, fqz);

  double hd[16];
#pragma unroll
  for (int i = 0; i < 16; ++i) hd[i] = __builtin_bit_cast(double, SENT_U64);

  const int cntv = scnt[qloc];
  if (cntv > CAP) {
    // overflow fallback (statistically ~9 sigma): exact rescan, raw formula
    for (int j = s16; j < N_; j += 16) {
      float cx = cb[j * 3 + 0], cy = cb[j * 3 + 1], cz = cb[j * 3 + 2];
      float ww = sq3(cx, cy, cz);
      float dot = fmaf(fqz, cz, fmaf(fqy, cy, fqx * cx));
      float d2;
      {
#pragma clang fp contract(off)
        d2 = (fxx + ww) - 2.0f * dot;
      }
      d2 = fmaxf(d2, 0.0f);
      double k = __builtin_bit_cast(double, pack_key_u64(d2, j));
      if (k < hd[15]) insert16(hd, k);
    }
  } else {
    for (int i = s16; i < cntv; i += 16) {
      int idx = sbuf[qloc][i];
      float d = exact_d(fqx, fqy, fqz, fxx, cg[idx]);
      double k = __builtin_bit_cast(double, pack_key_u64(d, idx));
      if (k < hd[15]) insert16(hd, k);
    }
  }

  // merge the 16 per-lane sorted lists -> top-16 (ascending (dist,idx))
  int* myout = idxout + ((size_t)(bb * N_ + n)) * K_;
#pragma unroll
  for (int r = 0; r < 16; ++r) {
    double v = hd[0];
    v = fmin(v, shfl_xor_f64(v, 1));
    v = fmin(v, shfl_xor_f64(v, 2));
    v = fmin(v, shfl_xor_f64(v, 4));
    v = fmin(v, shfl_xor_f64(v, 8));
    if (__builtin_bit_cast(uint64_t, hd[0]) == __builtin_bit_cast(uint64_t, v)) {
#pragma unroll
      for (int z = 0; z < 15; ++z) hd[z] = hd[z + 1];
      hd[15] = __builtin_bit_cast(double, SENT_U64);
    }
    if (s16 == 0) myout[r] = (int)(uint32_t)__builtin_bit_cast(uint64_t, v);
  }
}

// ---- stage 2 (LDS-free): direct gather -> in-register A fragments -> MFMA ----
// A-matrix row = neighbor k (lane&15), cols: 0-63 fi | 64-127 nf-fi | 128-130 pos.
// Lane (row,g) needs only fi/nf chunks [g*8..+7] and [32+g*8..+7]: 8 float4 loads.
// Cols >= 131 multiply zeroed wfrag rows -> values irrelevant (set 0).
__global__ __launch_bounds__(256) void stage2(const float* __restrict__ coords,
                                              const float* __restrict__ feat,
                                              const int* __restrict__ idxbuf,
                                              const __hip_bfloat16* __restrict__ wfrag,
                                              const float* __restrict__ bias,
                                              float* __restrict__ out) {
  const int t = threadIdx.x;
  const int w = t >> 6;
  const int lane = t & 63;
  const int q = blockIdx.x * 4 + w;
  const int bb = q >> 13;
  const int n = q & (N_ - 1);
  const float* cb = coords + (size_t)bb * N_ * 3;
  const float* fb = feat + (size_t)bb * N_ * C_;
  const int* myidx = idxbuf + (size_t)q * K_;

  const int row = lane & 15;   // neighbor index k; also D's col = output channel
  const int g = lane >> 4;
  const int nb = myidx[row];

  const float* fq = fb + (size_t)n * C_;
  const float* fn = fb + (size_t)nb * C_;

  float4 fi0 = *(const float4*)&fq[g * 8];
  float4 fi1 = *(const float4*)&fq[g * 8 + 4];
  float4 fi2 = *(const float4*)&fq[32 + g * 8];
  float4 fi3 = *(const float4*)&fq[32 + g * 8 + 4];
  float4 nf0 = *(const float4*)&fn[g * 8];
  float4 nf1 = *(const float4*)&fn[g * 8 + 4];
  float4 nf2 = *(const float4*)&fn[32 + g * 8];
  float4 nf3 = *(const float4*)&fn[32 + g * 8 + 4];

  short8v a[5];
  a[0] = (short8v){bfs(fi0.x), bfs(fi0.y), bfs(fi0.z), bfs(fi0.w),
                   bfs(fi1.x), bfs(fi1.y), bfs(fi1.z), bfs(fi1.w)};
  a[1] = (short8v){bfs(fi2.x), bfs(fi2.y), bfs(fi2.z), bfs(fi2.w),
                   bfs(fi3.x), bfs(fi3.y), bfs(fi3.z), bfs(fi3.w)};
  a[2] = (short8v){bfs(nf0.x - fi0.x), bfs(nf0.y - fi0.y), bfs(nf0.z - fi0.z), bfs(nf0.w - fi0.w),
                   bfs(nf1.x - fi1.x), bfs(nf1.y - fi1.y), bfs(nf1.z - fi1.z), bfs(nf1.w - fi1.w)};
  a[3] = (short8v){bfs(nf2.x - fi2.x), bfs(nf2.y - fi2.y), bfs(nf2.z - fi2.z), bfs(nf2.w - fi2.w),
                   bfs(nf3.x - fi3.x), bfs(nf3.y - fi3.y), bfs(nf3.z - fi3.z), bfs(nf3.w - fi3.w)};
  if (g == 0) {
    a[4] = (short8v){bfs(cb[nb * 3 + 0] - cb[n * 3 + 0]),
                     bfs(cb[nb * 3 + 1] - cb[n * 3 + 1]),
                     bfs(cb[nb * 3 + 2] - cb[n * 3 + 2]),
                     0, 0, 0, 0, 0};
  } else {
    a[4] = (short8v){0, 0, 0, 0, 0, 0, 0, 0};
  }

  const short8v* wf = (const short8v*)wfrag;
#pragma unroll
  for (int nt = 0; nt < 4; ++nt) {
    f32x4 acc = {0.f, 0.f, 0.f, 0.f};
#pragma unroll
    for (int ks = 0; ks < 5; ++ks) {
      short8v bf = wf[(nt * 5 + ks) * 64 + lane];
      acc = __builtin_amdgcn_mfma_f32_16x16x32_bf16(a[ks], bf, acc, 0, 0, 0);
    }
    float bcol = bias[nt * 16 + row];
    float m = fmaxf(fmaxf(fmaxf(acc[0] + bcol, 0.f), fmaxf(acc[1] + bcol, 0.f)),
                    fmaxf(fmaxf(acc[2] + bcol, 0.f), fmaxf(acc[3] + bcol, 0.f)));
    m = fmaxf(m, __shfl_xor(m, 16, 64));
    m = fmaxf(m, __shfl_xor(m, 32, 64));
    if (lane < 16) out[(size_t)q * C_ + nt * 16 + row] = m;
  }
}

extern "C" void kernel_launch(void* const* d_in, const int* in_sizes, int n_in,
                              void* d_out, int out_size, void* d_ws, size_t ws_size,
                              hipStream_t stream) {
  const float* coords = (const float*)d_in[0];
  const float* feat = (const float*)d_in[1];
  const float* W = (const float*)d_in[2];
  const float* bias = (const float*)d_in[3];
  float* out = (float*)d_out;

  int* ws_idx = (int*)d_ws;                                   // B*N*K ints = 1 MiB
  char* p = (char*)d_ws + (size_t)B_ * N_ * K_ * sizeof(int);
  __hip_bfloat16* wfrag = (__hip_bfloat16*)p;                 // 20 KiB
  float4* c4 = (float4*)(p + 32768);                          // 256 KiB, 16B-aligned

  const int prep_elems = 4 * 5 * 64 * 8 + B_ * N_;
  prep<<<(prep_elems + 255) / 256, 256, 0, stream>>>(coords, W, wfrag, c4);
  knn_kernel<<<(B_ * N_) / QPB, 256, 0, stream>>>(coords, c4, ws_idx);
  stage2<<<(B_ * N_) / 4, 256, 0, stream>>>(coords, feat, ws_idx, wfrag, bias, out);
}